// Round 5
// baseline (314.555 us; speedup 1.0000x reference)
//
#include <hip/hip_runtime.h>
#include <hip/hip_bf16.h>

typedef float f32x4 __attribute__((ext_vector_type(4)));
typedef __bf16 bf16x8 __attribute__((ext_vector_type(8)));

// ---------------------------------------------------------------------------
// GEMM1: h1(256x128) = x(256x256) @ w1(128x256)^T + b1
// ---------------------------------------------------------------------------
__global__ __launch_bounds__(128) void gemm1_k(const float* __restrict__ x,
                                               const float* __restrict__ w1,
                                               const float* __restrict__ b1,
                                               float* __restrict__ h1) {
    __shared__ float xs[256];
    const int m = blockIdx.x, t = threadIdx.x;
    xs[t] = x[m * 256 + t];
    xs[t + 128] = x[m * 256 + 128 + t];
    __syncthreads();
    float acc = b1[t];
    const float4* wr = (const float4*)(w1 + t * 256);
#pragma unroll 8
    for (int k4 = 0; k4 < 64; ++k4) {
        float4 w = wr[k4];
        acc += xs[k4 * 4 + 0] * w.x + xs[k4 * 4 + 1] * w.y +
               xs[k4 * 4 + 2] * w.z + xs[k4 * 4 + 3] * w.w;
    }
    h1[m * 128 + t] = acc;
}

// ---------------------------------------------------------------------------
// GEMM2: h2b = bf16 fragment-layout image of h1 @ w2^T + b2 (NO xor swizzle:
// gemm3 reads it from global, where there are no LDS bank conflicts and a
// linear layout makes each wave fragment-load 16 full cache lines).
// byte(m, n) = (n>>6)*32768 + m*128 + ((n&63)>>3)*16 + (n&7)*2
// ---------------------------------------------------------------------------
__global__ __launch_bounds__(256) void gemm2_k(const float* __restrict__ h1,
                                               const float* __restrict__ w2,
                                               const float* __restrict__ b2,
                                               char* __restrict__ h2b) {
    __shared__ float As[64][129];
    __shared__ float Bs[64][129];
    const int nb = blockIdx.x, mb = blockIdx.y, t = threadIdx.x;
#pragma unroll
    for (int i = 0; i < 8; ++i) {
        int idx = i * 256 + t;
        int row = idx >> 5, c4 = (idx & 31) * 4;
        float4 a = *(const float4*)(h1 + (mb * 64 + row) * 128 + c4);
        As[row][c4 + 0] = a.x; As[row][c4 + 1] = a.y;
        As[row][c4 + 2] = a.z; As[row][c4 + 3] = a.w;
        float4 bv = *(const float4*)(w2 + (nb * 64 + row) * 128 + c4);
        Bs[row][c4 + 0] = bv.x; Bs[row][c4 + 1] = bv.y;
        Bs[row][c4 + 2] = bv.z; Bs[row][c4 + 3] = bv.w;
    }
    __syncthreads();
    const int tx = t & 15, ty = t >> 4;
    float acc[4][4] = {};
#pragma unroll 4
    for (int k = 0; k < 128; ++k) {
        float a[4], b[4];
#pragma unroll
        for (int i = 0; i < 4; ++i) a[i] = As[ty * 4 + i][k];
#pragma unroll
        for (int j = 0; j < 4; ++j) b[j] = Bs[tx * 4 + j][k];
#pragma unroll
        for (int i = 0; i < 4; ++i)
#pragma unroll
            for (int j = 0; j < 4; ++j) acc[i][j] += a[i] * b[j];
    }
#pragma unroll
    for (int i = 0; i < 4; ++i)
#pragma unroll
        for (int j = 0; j < 4; ++j) {
            int m = mb * 64 + ty * 4 + i;
            int n = nb * 64 + tx * 4 + j;
            float v = acc[i][j] + b2[n];
            int kb = n >> 6, r = n & 63;
            int byte = kb * 32768 + m * 128 + (r >> 3) * 16 + (r & 7) * 2;
            *(__bf16*)(h2b + byte) = (__bf16)v;
        }
}

__device__ __forceinline__ bf16x8 pack8(const float4& lo, const float4& hi) {
    bf16x8 p;
    p[0] = (__bf16)lo.x; p[1] = (__bf16)lo.y; p[2] = (__bf16)lo.z; p[3] = (__bf16)lo.w;
    p[4] = (__bf16)hi.x; p[5] = (__bf16)hi.y; p[6] = (__bf16)hi.z; p[7] = (__bf16)hi.w;
    return p;
}

// ---------------------------------------------------------------------------
// GEMM3 v4: LDS-free, barrier-free. 512 thr (8 waves, 4M x 2N), grid 256.
// A fragments: per-lane bf16x8 direct from the 2MB L2-resident image.
// W fragments: per-lane 2x float4 direct from w3 (single-use HBM stream),
// cvt in regs. Explicit 2-deep register pipeline; waves fully independent.
// ---------------------------------------------------------------------------
__global__ __launch_bounds__(512) void gemm3_k(const char* __restrict__ Ab,
                                               const float* __restrict__ W,
                                               const float* __restrict__ bias,
                                               float* __restrict__ C) {
    const int tid = threadIdx.x;
    const int n0 = blockIdx.x * 64;
    const int lane = tid & 63, wid = tid >> 6;
    const int lr = lane & 15, lq = lane >> 4;
    const int wm = wid >> 1, wn = wid & 1;

    // lane-constant bases
    const char* Abase = Ab + (wm * 64 + lr) * 128 + lq * 16;   // + t*32768 + mi*2048 + kk*64
    const float* Wp = W + (size_t)(n0 + wn * 32 + lr) * 4096 + lq * 8;  // + ni*16*4096 + t*64 + kk*32

#define LOADA(dst, t)                                                   \
    {                                                                   \
        const char* _p = Abase + (t) * 32768;                           \
        _Pragma("unroll") for (int mi = 0; mi < 4; ++mi) {              \
            dst[mi][0] = *(const bf16x8*)(_p + mi * 2048);              \
            dst[mi][1] = *(const bf16x8*)(_p + mi * 2048 + 64);         \
        }                                                               \
    }
#define LOADW(d0, d1, t)                                                \
    {                                                                   \
        _Pragma("unroll") for (int ni = 0; ni < 2; ++ni) {              \
            const float* _q = Wp + ni * (16 * 4096) + (t) * 64;         \
            d0[ni][0] = *(const float4*)_q;                             \
            d1[ni][0] = *(const float4*)(_q + 4);                       \
            d0[ni][1] = *(const float4*)(_q + 32);                      \
            d1[ni][1] = *(const float4*)(_q + 36);                      \
        }                                                               \
    }
#define STEP(aR, w0R, w1R)                                                       \
    {                                                                            \
        _Pragma("unroll") for (int kk = 0; kk < 2; ++kk) {                       \
            bf16x8 bf0 = pack8(w0R[0][kk], w1R[0][kk]);                          \
            bf16x8 bf1 = pack8(w0R[1][kk], w1R[1][kk]);                          \
            _Pragma("unroll") for (int mi = 0; mi < 4; ++mi) {                   \
                acc[mi][0] = __builtin_amdgcn_mfma_f32_16x16x32_bf16(            \
                    aR[mi][kk], bf0, acc[mi][0], 0, 0, 0);                       \
                acc[mi][1] = __builtin_amdgcn_mfma_f32_16x16x32_bf16(            \
                    aR[mi][kk], bf1, acc[mi][1], 0, 0, 0);                       \
            }                                                                    \
        }                                                                        \
    }

    f32x4 acc[4][2];
    const f32x4 zero = {0.f, 0.f, 0.f, 0.f};
#pragma unroll
    for (int mi = 0; mi < 4; ++mi)
#pragma unroll
        for (int ni = 0; ni < 2; ++ni) acc[mi][ni] = zero;

    bf16x8 a0[4][2], a1[4][2];
    float4 wA0[2][2], wB0[2][2], wA1[2][2], wB1[2][2];

    LOADA(a0, 0);
    LOADW(wA0, wB0, 0);
#pragma unroll 1
    for (int t = 0; t < 64; t += 2) {
        LOADA(a1, t + 1);
        LOADW(wA1, wB1, t + 1);
        STEP(a0, wA0, wB0);
        const int t2 = (t + 2 < 64) ? t + 2 : 62;  // clamped redundant tail load
        LOADA(a0, t2);
        LOADW(wA0, wB0, t2);
        STEP(a1, wA1, wB1);
    }
#undef LOADA
#undef LOADW
#undef STEP

    float bv[2];
#pragma unroll
    for (int ni = 0; ni < 2; ++ni) bv[ni] = bias[n0 + wn * 32 + ni * 16 + lr];
#pragma unroll
    for (int mi = 0; mi < 4; ++mi)
#pragma unroll
        for (int ni = 0; ni < 2; ++ni) {
            const int n = n0 + wn * 32 + ni * 16 + lr;
#pragma unroll
            for (int r = 0; r < 4; ++r) {
                int m = wm * 64 + mi * 16 + lq * 4 + r;
                C[m * 16384 + n] = acc[mi][ni][r] + bv[ni];
            }
        }
}

// ---------------------------------------------------------------------------
// Fused conv x5 (bf16 MFMA) + square + Sinkhorn. One block per batch element.
// ---------------------------------------------------------------------------
template <int CIN, int COUT, int DIL, int MT, int NT>
__device__ __forceinline__ void conv_core(const char* xt, char* wl,
                                          const float* __restrict__ w,
                                          f32x4 (&acc)[MT][NT], int tid) {
    constexpr int RB = CIN * 2;
    const int lane = tid & 63, wid = tid >> 6;
    const int lr = lane & 15, lq = lane >> 4;
    const int cobase = wid * (COUT / 4);
    const f32x4 zero = {0.f, 0.f, 0.f, 0.f};
#pragma unroll
    for (int mi = 0; mi < MT; ++mi)
#pragma unroll
        for (int ni = 0; ni < NT; ++ni) acc[mi][ni] = zero;

    for (int cic = 0; cic < CIN / 32; ++cic) {
        for (int idx = tid; idx < COUT * 4; idx += 256) {
            int co = idx >> 2, cib = idx & 3, ci0 = cic * 32 + cib * 8;
            const float* src = w + co * (CIN * 3) + ci0 * 3;
            float v[24];
#pragma unroll
            for (int u = 0; u < 6; ++u) {
                float4 f = *(const float4*)(src + u * 4);
                v[u * 4 + 0] = f.x; v[u * 4 + 1] = f.y;
                v[u * 4 + 2] = f.z; v[u * 4 + 3] = f.w;
            }
#pragma unroll
            for (int tp = 0; tp < 3; ++tp) {
                bf16x8 pk;
#pragma unroll
                for (int j = 0; j < 8; ++j) pk[j] = (__bf16)v[j * 3 + tp];
                *(bf16x8*)(wl + ((tp * 4 + cib) * COUT + co) * 16) = pk;
            }
        }
        __syncthreads();
#pragma unroll
        for (int tp = 0; tp < 3; ++tp) {
            bf16x8 af[MT];
#pragma unroll
            for (int mi = 0; mi < MT; ++mi)
                af[mi] = *(const bf16x8*)(wl + ((tp * 4 + lq) * COUT + cobase + mi * 16 + lr) * 16);
            bf16x8 bfr[NT];
#pragma unroll
            for (int ni = 0; ni < NT; ++ni) {
                int colX = ni * 16 + lr + tp * DIL;
                bfr[ni] = *(const bf16x8*)(xt + ((colX * RB + (cic * 4 + lq) * 16) ^ ((colX & 7) << 4)));
            }
#pragma unroll
            for (int mi = 0; mi < MT; ++mi)
#pragma unroll
                for (int ni = 0; ni < NT; ++ni)
                    acc[mi][ni] = __builtin_amdgcn_mfma_f32_16x16x32_bf16(
                        af[mi], bfr[ni], acc[mi][ni], 0, 0, 0);
        }
        __syncthreads();
    }
}

template <int COUT, int LOUT, int MT, int NT>
__device__ __forceinline__ void write_xt(char* xt_out, const f32x4 (&acc)[MT][NT],
                                         const float* __restrict__ bias, int tid) {
    constexpr int RBO = COUT * 2;
    const int lane = tid & 63, wid = tid >> 6;
    const int lr = lane & 15, lq = lane >> 4;
    const int cobase = wid * (COUT / 4);
#pragma unroll
    for (int mi = 0; mi < MT; ++mi)
#pragma unroll
        for (int ni = 0; ni < NT; ++ni) {
            int l = ni * 16 + lr;
            if (l < LOUT) {
#pragma unroll
                for (int r = 0; r < 4; ++r) {
                    int co = cobase + mi * 16 + lq * 4 + r;
                    float y = acc[mi][ni][r] + bias[co];
                    int byte = (l * RBO + ((co >> 3) << 4) + (co & 7) * 2) ^ ((l & 7) << 4);
                    *(__bf16*)(xt_out + byte) = (__bf16)y;
                }
            }
        }
}

__global__ __launch_bounds__(256, 1) void convsink_k(
    const float* __restrict__ h3,
    const float* __restrict__ cw1, const float* __restrict__ cb1,
    const float* __restrict__ cw2, const float* __restrict__ cb2,
    const float* __restrict__ cw3, const float* __restrict__ cb3,
    const float* __restrict__ cw4, const float* __restrict__ cb4,
    const float* __restrict__ cw5, const float* __restrict__ cb5,
    float* __restrict__ out) {
    __shared__ __align__(16) char lds[34816 + 31488 + 36864 + 16640];
    char* xtA = lds;
    char* xtB = lds + 34816;
    char* wl = lds + 34816 + 31488;
    float* S = (float*)(lds + 34816 + 31488 + 36864);

    const int b = blockIdx.x, tid = threadIdx.x;
    const float* src = h3 + b * 16384;

#pragma unroll
    for (int i = 0; i < 8; ++i) {
        int idx = i * 256 + tid;
        int l = idx & 127, cib = idx >> 7;
        bf16x8 p;
#pragma unroll
        for (int j = 0; j < 8; ++j) p[j] = (__bf16)src[(cib * 8 + j) * 128 + l];
        *(bf16x8*)(xtA + ((l * 256 + cib * 16) ^ ((l & 7) << 4))) = p;
    }
    __syncthreads();

    {
        f32x4 acc[3][5];
        conv_core<128, 192, 28, 3, 5>(xtA, wl, cw1, acc, tid);
        write_xt<192, 72, 3, 5>(xtB, acc, cb1, tid);
    }
    __syncthreads();
    {
        f32x4 acc[2][5];
        conv_core<192, 128, 1, 2, 5>(xtB, wl, cw2, acc, tid);
        write_xt<128, 70, 2, 5>(xtA, acc, cb2, tid);
    }
    __syncthreads();
    {
        f32x4 acc[1][5];
        conv_core<128, 64, 1, 1, 5>(xtA, wl, cw3, acc, tid);
        write_xt<64, 68, 1, 5>(xtB, acc, cb3, tid);
    }
    __syncthreads();
    {
        f32x4 acc[1][5];
        conv_core<64, 64, 1, 1, 5>(xtB, wl, cw4, acc, tid);
        write_xt<64, 66, 1, 5>(xtA, acc, cb4, tid);
    }
    __syncthreads();
    {
        f32x4 acc[1][4];
        conv_core<64, 64, 1, 1, 4>(xtA, wl, cw5, acc, tid);
        const int lane = tid & 63, wid = tid >> 6;
        const int lr = lane & 15, lq = lane >> 4;
        const int cobase = wid * 16;
#pragma unroll
        for (int ni = 0; ni < 4; ++ni) {
            int l = ni * 16 + lr;
#pragma unroll
            for (int r = 0; r < 4; ++r) {
                int co = cobase + lq * 4 + r;
                float y = acc[0][ni][r] + cb5[co];
                S[co * 65 + l] = y * y + 0.001f;
            }
        }
    }
    __syncthreads();

    const int q = tid & 3, rid = tid >> 2;
    for (int it = 0; it < 10; ++it) {
        float p = 0.f;
#pragma unroll
        for (int j = 0; j < 16; ++j) p += S[rid * 65 + q * 16 + j];
        p += __shfl_xor(p, 1);
        p += __shfl_xor(p, 2);
        float inv = 1.0f / p;
#pragma unroll
        for (int j = 0; j < 16; ++j) S[rid * 65 + q * 16 + j] *= inv;
        __syncthreads();
        float c = 0.f;
#pragma unroll
        for (int i = 0; i < 16; ++i) c += S[(q * 16 + i) * 65 + rid];
        c += __shfl_xor(c, 1);
        c += __shfl_xor(c, 2);
        float invc = 1.0f / c;
#pragma unroll
        for (int i = 0; i < 16; ++i) S[(q * 16 + i) * 65 + rid] *= invc;
        __syncthreads();
    }

#pragma unroll
    for (int i = 0; i < 16; ++i) {
        int idx = i * 256 + tid;
        out[b * 4096 + idx] = S[(idx >> 6) * 65 + (idx & 63)];
    }
}

// ---------------------------------------------------------------------------
extern "C" void kernel_launch(void* const* d_in, const int* in_sizes, int n_in,
                              void* d_out, int out_size, void* d_ws, size_t ws_size,
                              hipStream_t stream) {
    const float* x = (const float*)d_in[0];
    const float* w1 = (const float*)d_in[1];
    const float* b1 = (const float*)d_in[2];
    const float* w2 = (const float*)d_in[3];
    const float* b2 = (const float*)d_in[4];
    const float* w3 = (const float*)d_in[5];
    const float* b3 = (const float*)d_in[6];
    const float* cw1 = (const float*)d_in[7];
    const float* cb1 = (const float*)d_in[8];
    const float* cw2 = (const float*)d_in[9];
    const float* cb2 = (const float*)d_in[10];
    const float* cw3 = (const float*)d_in[11];
    const float* cb3 = (const float*)d_in[12];
    const float* cw4 = (const float*)d_in[13];
    const float* cb4 = (const float*)d_in[14];
    const float* cw5 = (const float*)d_in[15];
    const float* cb5 = (const float*)d_in[16];
    float* out = (float*)d_out;

    char* ws = (char*)d_ws;
    float* h1 = (float*)(ws);                       // 131072 B
    char* h2b = ws + 131072;                        // 2 MB bf16 image
    float* h3 = (float*)(ws + 131072 + 2097152);    // 16777216 B

    gemm1_k<<<256, 128, 0, stream>>>(x, w1, b1, h1);
    gemm2_k<<<dim3(64, 4), 256, 0, stream>>>(h1, w2, b2, h2b);
    gemm3_k<<<256, 512, 0, stream>>>(h2b, w3, b3, h3);
    convsink_k<<<256, 256, 0, stream>>>(h3, cw1, cb1, cw2, cb2, cw3, cb3,
                                        cw4, cb4, cw5, cb5, out);
}

// Round 6
// 131.157 us; speedup vs baseline: 2.3983x; 2.3983x over previous
//
#include <hip/hip_runtime.h>
#include <hip/hip_bf16.h>

typedef float f32x4 __attribute__((ext_vector_type(4)));
typedef __bf16 bf16x8 __attribute__((ext_vector_type(8)));

typedef __attribute__((address_space(1))) const unsigned int as1_uint;
typedef __attribute__((address_space(3))) unsigned int as3_uint;

// ---------------------------------------------------------------------------
// GEMM1: h1(256x128) = x(256x256) @ w1(128x256)^T + b1
// ---------------------------------------------------------------------------
__global__ __launch_bounds__(128) void gemm1_k(const float* __restrict__ x,
                                               const float* __restrict__ w1,
                                               const float* __restrict__ b1,
                                               float* __restrict__ h1) {
    __shared__ float xs[256];
    const int m = blockIdx.x, t = threadIdx.x;
    xs[t] = x[m * 256 + t];
    xs[t + 128] = x[m * 256 + 128 + t];
    __syncthreads();
    float acc = b1[t];
    const float4* wr = (const float4*)(w1 + t * 256);
#pragma unroll 8
    for (int k4 = 0; k4 < 64; ++k4) {
        float4 w = wr[k4];
        acc += xs[k4 * 4 + 0] * w.x + xs[k4 * 4 + 1] * w.y +
               xs[k4 * 4 + 2] * w.z + xs[k4 * 4 + 3] * w.w;
    }
    h1[m * 128 + t] = acc;
}

// ---------------------------------------------------------------------------
// GEMM2: h2b = bf16 pre-swizzled "LDS image" of h1 @ w2^T + b2.
// byte(m, n) = (n>>6)*32768 + ((m*128 + ((n&63)>>3)*16) ^ ((m&7)<<4)) + (n&7)*2
// (exactly the A-tile byte layout gemm3's swizzled MFMA fragment reads expect)
// ---------------------------------------------------------------------------
__global__ __launch_bounds__(256) void gemm2_k(const float* __restrict__ h1,
                                               const float* __restrict__ w2,
                                               const float* __restrict__ b2,
                                               char* __restrict__ h2b) {
    __shared__ float As[64][129];
    __shared__ float Bs[64][129];
    const int nb = blockIdx.x, mb = blockIdx.y, t = threadIdx.x;
#pragma unroll
    for (int i = 0; i < 8; ++i) {
        int idx = i * 256 + t;
        int row = idx >> 5, c4 = (idx & 31) * 4;
        float4 a = *(const float4*)(h1 + (mb * 64 + row) * 128 + c4);
        As[row][c4 + 0] = a.x; As[row][c4 + 1] = a.y;
        As[row][c4 + 2] = a.z; As[row][c4 + 3] = a.w;
        float4 bv = *(const float4*)(w2 + (nb * 64 + row) * 128 + c4);
        Bs[row][c4 + 0] = bv.x; Bs[row][c4 + 1] = bv.y;
        Bs[row][c4 + 2] = bv.z; Bs[row][c4 + 3] = bv.w;
    }
    __syncthreads();
    const int tx = t & 15, ty = t >> 4;
    float acc[4][4] = {};
#pragma unroll 4
    for (int k = 0; k < 128; ++k) {
        float a[4], b[4];
#pragma unroll
        for (int i = 0; i < 4; ++i) a[i] = As[ty * 4 + i][k];
#pragma unroll
        for (int j = 0; j < 4; ++j) b[j] = Bs[tx * 4 + j][k];
#pragma unroll
        for (int i = 0; i < 4; ++i)
#pragma unroll
            for (int j = 0; j < 4; ++j) acc[i][j] += a[i] * b[j];
    }
#pragma unroll
    for (int i = 0; i < 4; ++i)
#pragma unroll
        for (int j = 0; j < 4; ++j) {
            int m = mb * 64 + ty * 4 + i;
            int n = nb * 64 + tx * 4 + j;
            float v = acc[i][j] + b2[n];
            int kb = n >> 6, r = n & 63;
            int byte = kb * 32768 + ((m * 128 + (r >> 3) * 16) ^ ((m & 7) << 4)) + (r & 7) * 2;
            *(__bf16*)(h2b + byte) = (__bf16)v;
        }
}

// ---------------------------------------------------------------------------
// GEMM3 v5: r3 LDS structure + K-SPLIT 2 for occupancy.
// grid 512: block = (nb, ks); ks-half of K (32 of 64 K-steps). 512 thr, 8 waves.
// LDS 80KB -> 2 blocks/CU = 16 waves/CU; co-resident blocks are independent,
// so barrier/vmcnt drains of one block overlap the other block's compute.
// Output: bf16 PARTIALS (no bias) to parts[ks]; convsink sums p0+p1+b3.
// ---------------------------------------------------------------------------
__global__ __launch_bounds__(512, 1) void gemm3_k(const char* __restrict__ Ab,
                                                  const float* __restrict__ W,
                                                  char* __restrict__ parts) {
    __shared__ __align__(16) char lds[81920];
    const int tid = threadIdx.x;
    const int nb = blockIdx.x >> 1, ks = blockIdx.x & 1;
    const int n0 = nb * 64;
    const int lane = tid & 63, wid = tid >> 6;
    const int mrow = tid >> 3, kb8 = tid & 7;

#define ISSUE_A(kt, buf)                                                            \
    {                                                                               \
        const char* _s = Ab + (kt) * 32768 + wid * 4096 + lane * 16;                \
        char* _d = lds + (buf) * 32768 + wid * 4096;                                \
        __builtin_amdgcn_global_load_lds((as1_uint*)(_s), (as3_uint*)(_d), 16, 0, 0);             \
        __builtin_amdgcn_global_load_lds((as1_uint*)(_s + 1024), (as3_uint*)(_d + 1024), 16, 0, 0); \
        __builtin_amdgcn_global_load_lds((as1_uint*)(_s + 2048), (as3_uint*)(_d + 2048), 16, 0, 0); \
        __builtin_amdgcn_global_load_lds((as1_uint*)(_s + 3072), (as3_uint*)(_d + 3072), 16, 0, 0); \
    }

    float4 w0r, w1r;
    auto loadW = [&](int kt) {
        const float* q = W + (n0 + mrow) * 4096 + kt * 64 + kb8 * 8;
        w0r = *(const float4*)q;
        w1r = *(const float4*)(q + 4);
    };
    auto storeW = [&](int buf) {
        bf16x8 p;
        p[0] = (__bf16)w0r.x; p[1] = (__bf16)w0r.y; p[2] = (__bf16)w0r.z; p[3] = (__bf16)w0r.w;
        p[4] = (__bf16)w1r.x; p[5] = (__bf16)w1r.y; p[6] = (__bf16)w1r.z; p[7] = (__bf16)w1r.w;
        *(bf16x8*)(lds + 65536 + buf * 8192 +
                   ((mrow * 128 + kb8 * 16) ^ ((mrow & 7) << 4))) = p;
    };

    const int kt0 = ks * 32;

    // prologue: tile kt0
    ISSUE_A(kt0, 0);
    loadW(kt0);
    __syncthreads();   // drain: A(kt0) resident, w regs ready
    storeW(0);
    __syncthreads();   // W(kt0) visible

    const int lr = lane & 15, lq = lane >> 4;
    const int wm = wid >> 1, wn = wid & 1;

    f32x4 acc[4][2];
    const f32x4 zero = {0.f, 0.f, 0.f, 0.f};
#pragma unroll
    for (int mi = 0; mi < 4; ++mi)
#pragma unroll
        for (int ni = 0; ni < 2; ++ni) acc[mi][ni] = zero;

    for (int t = 0; t < 32; ++t) {
        const int cur = t & 1;
        if (t < 31) {
            ISSUE_A(kt0 + t + 1, cur ^ 1);
            loadW(kt0 + t + 1);
        }
        const char* Ac = lds + cur * 32768;
        const char* Wc = lds + 65536 + cur * 8192;
#pragma unroll
        for (int kk = 0; kk < 2; ++kk) {
            const int kb = kk * 4 + lq;
            bf16x8 af[4], bfv[2];
#pragma unroll
            for (int mi = 0; mi < 4; ++mi) {
                int m = wm * 64 + mi * 16 + lr;
                af[mi] = *(const bf16x8*)(Ac + ((m * 128 + kb * 16) ^ ((m & 7) << 4)));
            }
#pragma unroll
            for (int ni = 0; ni < 2; ++ni) {
                int n = wn * 32 + ni * 16 + lr;
                bfv[ni] = *(const bf16x8*)(Wc + ((n * 128 + kb * 16) ^ ((n & 7) << 4)));
            }
#pragma unroll
            for (int mi = 0; mi < 4; ++mi)
#pragma unroll
                for (int ni = 0; ni < 2; ++ni)
                    acc[mi][ni] = __builtin_amdgcn_mfma_f32_16x16x32_bf16(
                        af[mi], bfv[ni], acc[mi][ni], 0, 0, 0);
        }
        __syncthreads();
        if (t < 31) storeW(cur ^ 1);
        __syncthreads();
    }
#undef ISSUE_A

    __bf16* P = (__bf16*)(parts + ks * 8388608);
#pragma unroll
    for (int mi = 0; mi < 4; ++mi)
#pragma unroll
        for (int ni = 0; ni < 2; ++ni) {
            const int n = n0 + wn * 32 + ni * 16 + lr;
#pragma unroll
            for (int r = 0; r < 4; ++r) {
                int m = wm * 64 + mi * 16 + lq * 4 + r;
                P[m * 16384 + n] = (__bf16)acc[mi][ni][r];
            }
        }
}

// ---------------------------------------------------------------------------
// Fused conv x5 (bf16 MFMA) + square + Sinkhorn. One block per batch element.
// Staging now sums the two gemm3 partials and adds b3.
// ---------------------------------------------------------------------------
template <int CIN, int COUT, int DIL, int MT, int NT>
__device__ __forceinline__ void conv_core(const char* xt, char* wl,
                                          const float* __restrict__ w,
                                          f32x4 (&acc)[MT][NT], int tid) {
    constexpr int RB = CIN * 2;
    const int lane = tid & 63, wid = tid >> 6;
    const int lr = lane & 15, lq = lane >> 4;
    const int cobase = wid * (COUT / 4);
    const f32x4 zero = {0.f, 0.f, 0.f, 0.f};
#pragma unroll
    for (int mi = 0; mi < MT; ++mi)
#pragma unroll
        for (int ni = 0; ni < NT; ++ni) acc[mi][ni] = zero;

    for (int cic = 0; cic < CIN / 32; ++cic) {
        for (int idx = tid; idx < COUT * 4; idx += 256) {
            int co = idx >> 2, cib = idx & 3, ci0 = cic * 32 + cib * 8;
            const float* src = w + co * (CIN * 3) + ci0 * 3;
            float v[24];
#pragma unroll
            for (int u = 0; u < 6; ++u) {
                float4 f = *(const float4*)(src + u * 4);
                v[u * 4 + 0] = f.x; v[u * 4 + 1] = f.y;
                v[u * 4 + 2] = f.z; v[u * 4 + 3] = f.w;
            }
#pragma unroll
            for (int tp = 0; tp < 3; ++tp) {
                bf16x8 pk;
#pragma unroll
                for (int j = 0; j < 8; ++j) pk[j] = (__bf16)v[j * 3 + tp];
                *(bf16x8*)(wl + ((tp * 4 + cib) * COUT + co) * 16) = pk;
            }
        }
        __syncthreads();
#pragma unroll
        for (int tp = 0; tp < 3; ++tp) {
            bf16x8 af[MT];
#pragma unroll
            for (int mi = 0; mi < MT; ++mi)
                af[mi] = *(const bf16x8*)(wl + ((tp * 4 + lq) * COUT + cobase + mi * 16 + lr) * 16);
            bf16x8 bfr[NT];
#pragma unroll
            for (int ni = 0; ni < NT; ++ni) {
                int colX = ni * 16 + lr + tp * DIL;
                bfr[ni] = *(const bf16x8*)(xt + ((colX * RB + (cic * 4 + lq) * 16) ^ ((colX & 7) << 4)));
            }
#pragma unroll
            for (int mi = 0; mi < MT; ++mi)
#pragma unroll
                for (int ni = 0; ni < NT; ++ni)
                    acc[mi][ni] = __builtin_amdgcn_mfma_f32_16x16x32_bf16(
                        af[mi], bfr[ni], acc[mi][ni], 0, 0, 0);
        }
        __syncthreads();
    }
}

template <int COUT, int LOUT, int MT, int NT>
__device__ __forceinline__ void write_xt(char* xt_out, const f32x4 (&acc)[MT][NT],
                                         const float* __restrict__ bias, int tid) {
    constexpr int RBO = COUT * 2;
    const int lane = tid & 63, wid = tid >> 6;
    const int lr = lane & 15, lq = lane >> 4;
    const int cobase = wid * (COUT / 4);
#pragma unroll
    for (int mi = 0; mi < MT; ++mi)
#pragma unroll
        for (int ni = 0; ni < NT; ++ni) {
            int l = ni * 16 + lr;
            if (l < LOUT) {
#pragma unroll
                for (int r = 0; r < 4; ++r) {
                    int co = cobase + mi * 16 + lq * 4 + r;
                    float y = acc[mi][ni][r] + bias[co];
                    int byte = (l * RBO + ((co >> 3) << 4) + (co & 7) * 2) ^ ((l & 7) << 4);
                    *(__bf16*)(xt_out + byte) = (__bf16)y;
                }
            }
        }
}

__global__ __launch_bounds__(256, 1) void convsink_k(
    const char* __restrict__ parts, const float* __restrict__ b3,
    const float* __restrict__ cw1, const float* __restrict__ cb1,
    const float* __restrict__ cw2, const float* __restrict__ cb2,
    const float* __restrict__ cw3, const float* __restrict__ cb3,
    const float* __restrict__ cw4, const float* __restrict__ cb4,
    const float* __restrict__ cw5, const float* __restrict__ cb5,
    float* __restrict__ out) {
    __shared__ __align__(16) char lds[34816 + 31488 + 36864 + 16640];
    char* xtA = lds;
    char* xtB = lds + 34816;
    char* wl = lds + 34816 + 31488;
    float* S = (float*)(lds + 34816 + 31488 + 36864);

    const int b = blockIdx.x, tid = threadIdx.x;
    const __bf16* p0 = (const __bf16*)parts + (size_t)b * 16384;
    const __bf16* p1 = (const __bf16*)(parts + 8388608) + (size_t)b * 16384;

#pragma unroll
    for (int i = 0; i < 8; ++i) {
        int idx = i * 256 + tid;
        int l = idx & 127, cib = idx >> 7;
        bf16x8 p;
#pragma unroll
        for (int j = 0; j < 8; ++j) {
            int n = (cib * 8 + j) * 128 + l;
            float v = (float)p0[n] + (float)p1[n] + b3[n];
            p[j] = (__bf16)v;
        }
        *(bf16x8*)(xtA + ((l * 256 + cib * 16) ^ ((l & 7) << 4))) = p;
    }
    __syncthreads();

    {
        f32x4 acc[3][5];
        conv_core<128, 192, 28, 3, 5>(xtA, wl, cw1, acc, tid);
        write_xt<192, 72, 3, 5>(xtB, acc, cb1, tid);
    }
    __syncthreads();
    {
        f32x4 acc[2][5];
        conv_core<192, 128, 1, 2, 5>(xtB, wl, cw2, acc, tid);
        write_xt<128, 70, 2, 5>(xtA, acc, cb2, tid);
    }
    __syncthreads();
    {
        f32x4 acc[1][5];
        conv_core<128, 64, 1, 1, 5>(xtA, wl, cw3, acc, tid);
        write_xt<64, 68, 1, 5>(xtB, acc, cb3, tid);
    }
    __syncthreads();
    {
        f32x4 acc[1][5];
        conv_core<64, 64, 1, 1, 5>(xtB, wl, cw4, acc, tid);
        write_xt<64, 66, 1, 5>(xtA, acc, cb4, tid);
    }
    __syncthreads();
    {
        f32x4 acc[1][4];
        conv_core<64, 64, 1, 1, 4>(xtA, wl, cw5, acc, tid);
        const int lane = tid & 63, wid = tid >> 6;
        const int lr = lane & 15, lq = lane >> 4;
        const int cobase = wid * 16;
#pragma unroll
        for (int ni = 0; ni < 4; ++ni) {
            int l = ni * 16 + lr;
#pragma unroll
            for (int r = 0; r < 4; ++r) {
                int co = cobase + lq * 4 + r;
                float y = acc[0][ni][r] + cb5[co];
                S[co * 65 + l] = y * y + 0.001f;
            }
        }
    }
    __syncthreads();

    const int q = tid & 3, rid = tid >> 2;
    for (int it = 0; it < 10; ++it) {
        float p = 0.f;
#pragma unroll
        for (int j = 0; j < 16; ++j) p += S[rid * 65 + q * 16 + j];
        p += __shfl_xor(p, 1);
        p += __shfl_xor(p, 2);
        float inv = 1.0f / p;
#pragma unroll
        for (int j = 0; j < 16; ++j) S[rid * 65 + q * 16 + j] *= inv;
        __syncthreads();
        float c = 0.f;
#pragma unroll
        for (int i = 0; i < 16; ++i) c += S[(q * 16 + i) * 65 + rid];
        c += __shfl_xor(c, 1);
        c += __shfl_xor(c, 2);
        float invc = 1.0f / c;
#pragma unroll
        for (int i = 0; i < 16; ++i) S[(q * 16 + i) * 65 + rid] *= invc;
        __syncthreads();
    }

#pragma unroll
    for (int i = 0; i < 16; ++i) {
        int idx = i * 256 + tid;
        out[b * 4096 + idx] = S[(idx >> 6) * 65 + (idx & 63)];
    }
}

// ---------------------------------------------------------------------------
extern "C" void kernel_launch(void* const* d_in, const int* in_sizes, int n_in,
                              void* d_out, int out_size, void* d_ws, size_t ws_size,
                              hipStream_t stream) {
    const float* x = (const float*)d_in[0];
    const float* w1 = (const float*)d_in[1];
    const float* b1 = (const float*)d_in[2];
    const float* w2 = (const float*)d_in[3];
    const float* b2 = (const float*)d_in[4];
    const float* w3 = (const float*)d_in[5];
    const float* b3 = (const float*)d_in[6];
    const float* cw1 = (const float*)d_in[7];
    const float* cb1 = (const float*)d_in[8];
    const float* cw2 = (const float*)d_in[9];
    const float* cb2 = (const float*)d_in[10];
    const float* cw3 = (const float*)d_in[11];
    const float* cb3 = (const float*)d_in[12];
    const float* cw4 = (const float*)d_in[13];
    const float* cb4 = (const float*)d_in[14];
    const float* cw5 = (const float*)d_in[15];
    const float* cb5 = (const float*)d_in[16];
    float* out = (float*)d_out;

    char* ws = (char*)d_ws;
    float* h1 = (float*)(ws);          // 131072 B
    char* h2b = ws + 131072;           // 2 MB bf16 pre-swizzled image
    char* parts = ws + 131072 + 2097152;  // 2 x 8 MB bf16 partials

    gemm1_k<<<256, 128, 0, stream>>>(x, w1, b1, h1);
    gemm2_k<<<dim3(64, 4), 256, 0, stream>>>(h1, w2, b2, h2b);
    gemm3_k<<<512, 512, 0, stream>>>(h2b, w3, parts);
    convsink_k<<<256, 256, 0, stream>>>(parts, b3, cw1, cb1, cw2, cb2,
                                        cw3, cb3, cw4, cb4, cw5, cb5, out);
}